// Round 1
// baseline (141.255 us; speedup 1.0000x reference)
//
#include <hip/hip_runtime.h>
#include <math.h>

#define B_MOL 64
#define MAXN 28
#define NSPEC 4
#define NRS2 24
#define NRS3 20
#define NPAIR 10
#define REP2_LEN (NSPEC * NRS2)          // 96
#define REP3_LEN (NPAIR * NRS3 * 2)      // 400
#define OUT_LEN (REP2_LEN + REP3_LEN)    // 496
#define RCUT 8.0f
#define ETA2 0.32f
#define ETA3 2.7f
#define PI_F 3.14159265358979323846f
// sqrt(2.7/pi)*13.4 computed in double, cast to f32
#define W3 12.4225783348083f

__global__ __launch_bounds__(64) void fchl_kernel(
    const float* __restrict__ X,      // [B][MAXN][3]
    const float* __restrict__ Z,      // [B][MAXN]
    const int* __restrict__ counts,   // [B]
    float* __restrict__ out)          // [B][MAXN][OUT_LEN]
{
    const int i = blockIdx.x;      // atom index within molecule
    const int b = blockIdx.y;      // molecule
    const int tid = threadIdx.x;
    const int cnt = counts[b];

    __shared__ float sx[MAXN], sy[MAXN], sz[MAXN];
    __shared__ int   sspec[MAXN];
    __shared__ float s_r[MAXN], s_fc[MAXN], s_ln[MAXN], s_mu[MAXN], s_pref[MAXN];
    __shared__ int   s_within[MAXN];
    __shared__ int   s_nbr[MAXN];
    __shared__ int   s_nn;
    __shared__ float rep3[REP3_LEN];

    // ---- load molecule data ----
    if (tid < MAXN) {
        sx[tid] = X[(b * MAXN + tid) * 3 + 0];
        sy[tid] = X[(b * MAXN + tid) * 3 + 1];
        sz[tid] = X[(b * MAXN + tid) * 3 + 2];
        float z = Z[b * MAXN + tid];
        int s = -1;
        if (z == 1.0f) s = 0;
        else if (z == 6.0f) s = 1;
        else if (z == 7.0f) s = 2;
        else if (z == 8.0f) s = 3;
        sspec[tid] = s;
    }
    for (int t = tid; t < REP3_LEN; t += 64) rep3[t] = 0.0f;
    __syncthreads();

    const bool valid_i = (i < cnt);

    // ---- per-neighbor-j quantities ----
    if (tid < MAXN) {
        const int j = tid;
        float dx = sx[i] - sx[j], dy = sy[i] - sy[j], dz = sz[i] - sz[j];
        float d2 = dx * dx + dy * dy + dz * dz;
        float r = sqrtf(d2);
        bool w = valid_i && (j < cnt) && (j != i) && (r < RCUT);
        s_within[j] = w ? 1 : 0;
        if (w) {
            float fc = 0.5f * (cosf(PI_F * r * (1.0f / RCUT)) + 1.0f);
            float ln = log1pf(ETA2 / (r * r));
            float mu = logf(r) - 0.5f * ln;
            s_r[j] = r;
            s_fc[j] = fc;
            s_ln[j] = ln;
            s_mu[j] = mu;
            s_pref[j] = fc * powf(r, -1.8f) * rsqrtf(ln);
        } else {
            s_r[j] = 1.0f; s_fc[j] = 0.0f; s_ln[j] = 1.0f;
            s_mu[j] = 0.0f; s_pref[j] = 0.0f;
        }
    }
    if (tid == 0) {
        int nn = 0;
        for (int j = 0; j < MAXN; ++j)
            if (s_within[j]) s_nbr[nn++] = j;
        s_nn = nn;
    }
    __syncthreads();

    float* orow = out + (size_t)(b * MAXN + i) * OUT_LEN;

    // ---- two-body: thread m owns radial bin m ----
    if (tid < NRS2) {
        const int m = tid;
        float rs2 = (float)(m + 1) * (8.0f / 24.0f);
        float lrs2 = logf(rs2);
        const float inv_s2pi = 0.3989422804014327f;  // 1/sqrt(2*pi)
        float nrm = inv_s2pi / rs2;
        float acc0 = 0.f, acc1 = 0.f, acc2 = 0.f, acc3 = 0.f;
        for (int j = 0; j < MAXN; ++j) {
            if (!s_within[j]) continue;
            float d = lrs2 - s_mu[j];
            float v = s_pref[j] * nrm * expf(-d * d / (2.0f * s_ln[j]));
            int s = sspec[j];
            if (s == 0) acc0 += v;
            else if (s == 1) acc1 += v;
            else if (s == 2) acc2 += v;
            else acc3 += v;
        }
        orow[0 * NRS2 + m] = acc0;
        orow[1 * NRS2 + m] = acc1;
        orow[2 * NRS2 + m] = acc2;
        orow[3 * NRS2 + m] = acc3;
    }

    // ---- three-body: pairs (j<k) of neighbors of i ----
    const int nn = s_nn;
    const int np = nn * (nn - 1) / 2;
    for (int idx = tid; idx < np; idx += 64) {
        // triangular decode idx -> (a, bb) with a < bb over nbr list
        int a = 0, rem = idx;
        while (rem >= nn - 1 - a) { rem -= nn - 1 - a; ++a; }
        int bb = a + 1 + rem;
        int j = s_nbr[a], k = s_nbr[bb];   // j < k guaranteed (sorted list)

        float rij = s_r[j], rik = s_r[k];
        float dx = sx[j] - sx[k], dy = sy[j] - sy[k], dz = sz[j] - sz[k];
        float rjk = sqrtf(dx * dx + dy * dy + dz * dz);

        float rij2 = rij * rij, rik2 = rik * rik, rjk2 = rjk * rjk;
        float cos_i = (rij2 + rik2 - rjk2) / (2.0f * rij * rik);
        float cos_j = (rij2 + rjk2 - rik2) / (2.0f * rij * rjk);
        float cos_k = (rik2 + rjk2 - rij2) / (2.0f * rik * rjk);

        float atm = (1.0f + 3.0f * cos_i * cos_j * cos_k)
                    * powf(rij * rik * rjk, -0.57f);
        float w = W3 * atm * s_fc[j] * s_fc[k];

        float c = fminf(fmaxf(cos_i, -1.0f), 1.0f);
        float sn = sqrtf(fminf(fmaxf(1.0f - c * c, 1e-12f), 1.0f));
        float wa0 = 2.0f * c * w;
        float wa1 = 2.0f * sn * w;
        float avg = 0.5f * (rij + rik);

        int pj = sspec[j], pk = sspec[k];
        int p = min(pj, pk), q = max(pj, pk);
        int P = p * NSPEC - p * (p - 1) / 2 + (q - p);
        float* dst = rep3 + P * (NRS3 * 2);

        #pragma unroll
        for (int l = 0; l < NRS3; ++l) {
            float dd = avg - 0.4f * (float)(l + 1);
            float e = expf(-ETA3 * dd * dd);
            atomicAdd(&dst[l * 2 + 0], wa0 * e);
            atomicAdd(&dst[l * 2 + 1], wa1 * e);
        }
    }
    __syncthreads();

    // ---- write rep3 ----
    for (int t = tid; t < REP3_LEN; t += 64)
        orow[REP2_LEN + t] = rep3[t];
}

extern "C" void kernel_launch(void* const* d_in, const int* in_sizes, int n_in,
                              void* d_out, int out_size, void* d_ws, size_t ws_size,
                              hipStream_t stream) {
    const float* X = (const float*)d_in[0];
    const float* Z = (const float*)d_in[1];
    // d_in[2] = atomIDs, d_in[3] = molIDs (unused by reference math)
    const int* counts = (const int*)d_in[4];
    float* out = (float*)d_out;

    dim3 grid(MAXN, B_MOL);   // one block per (atom i, molecule b)
    dim3 block(64);
    hipLaunchKernelGGL(fchl_kernel, grid, block, 0, stream, X, Z, counts, out);
}

// Round 3
// 20.686 us; speedup vs baseline: 6.8287x; 6.8287x over previous
//
#include <hip/hip_runtime.h>

#define B_MOL 64
#define MAXN 28
#define NSPEC 4
#define NRS2 24
#define NRS3 20
#define NPAIR 10
#define NCOMB 378                       // 28*27/2 fixed (j<k) combos
#define REP2_LEN (NSPEC * NRS2)         // 96
#define REP3_LEN (NPAIR * NRS3 * 2)     // 400
#define OUT_LEN (REP2_LEN + REP3_LEN)   // 496
#define RCUT 8.0f
#define ETA2 0.32f
#define ETA3 2.7f
#define LOG2E 1.4426950408889634f
#define LN2F 0.6931471805599453f
// sqrt(2.7/pi)*13.4 computed in double, cast to f32
#define W3 12.4225783348083f

// hardware transcendentals (raw gfx950 instructions, no libm namespace)
__device__ __forceinline__ float hexp2(float x) { return __builtin_amdgcn_exp2f(x); }
__device__ __forceinline__ float hlog2(float x) { return __builtin_amdgcn_logf(x); }
__device__ __forceinline__ float hrcp(float x)  { return __builtin_amdgcn_rcpf(x); }
__device__ __forceinline__ float hrsq(float x)  { return __builtin_amdgcn_rsqf(x); }
// cos(2*pi*t), t in revolutions
__device__ __forceinline__ float hcos_rev(float t) { return __builtin_amdgcn_cosf(t); }

// decode linear idx in [0,378) -> (j,k), j<k<28.
__device__ __forceinline__ void decode_pair(int idx, int& j, int& k) {
    int jj = (int)((55.0f - sqrtf(3025.0f - 8.0f * (float)idx)) * 0.5f);
    while (27 * (jj + 1) - ((jj + 1) * jj) / 2 <= idx) ++jj;
    while (27 * jj - (jj * (jj - 1)) / 2 > idx) --jj;
    int off = 27 * jj - (jj * (jj - 1)) / 2;
    j = jj;
    k = jj + 1 + (idx - off);
}

__global__ __launch_bounds__(256) void fchl_kernel(
    const float* __restrict__ X,      // [B][MAXN][3]
    const float* __restrict__ Z,      // [B][MAXN]
    const int* __restrict__ counts,   // [B]
    float* __restrict__ out)          // [B][MAXN][OUT_LEN]
{
    const int i = blockIdx.x;      // atom index within molecule
    const int b = blockIdx.y;      // molecule
    const int tid = threadIdx.x;
    const int cnt = counts[b];

    __shared__ float sx[MAXN], sy[MAXN], szc[MAXN];
    __shared__ int   sspec[MAXN];
    __shared__ int   s_win[MAXN];
    __shared__ float s_r[MAXN], s_fc[MAXN], s_mu[MAXN], s_i2ln[MAXN], s_pref[MAXN];
    __shared__ int   cntP[NPAIR], curP[NPAIR], baseP[NPAIR];
    __shared__ float4 s_pair[NCOMB];

    // ---- phase 0: load molecule ----
    if (tid < MAXN) {
        sx[tid]  = X[(b * MAXN + tid) * 3 + 0];
        sy[tid]  = X[(b * MAXN + tid) * 3 + 1];
        szc[tid] = X[(b * MAXN + tid) * 3 + 2];
        float z = Z[b * MAXN + tid];
        int s = -1;
        if (z == 1.0f) s = 0;
        else if (z == 6.0f) s = 1;
        else if (z == 7.0f) s = 2;
        else if (z == 8.0f) s = 3;
        sspec[tid] = s;
    }
    if (tid < NPAIR) cntP[tid] = 0;
    __syncthreads();

    const bool valid_i = (i < cnt);

    // ---- phase 1: per-neighbor-j quantities ----
    if (tid < MAXN) {
        const int j = tid;
        float dx = sx[i] - sx[j], dy = sy[i] - sy[j], dz = szc[i] - szc[j];
        float r = sqrtf(dx * dx + dy * dy + dz * dz);
        bool w = valid_i && (j < cnt) && (j != i) && (r < RCUT);
        s_win[j] = w ? 1 : 0;
        if (w) {
            // fc = 0.5*(cos(pi*r/8)+1) = 0.5*(cos(2pi * r/16)+1)
            float fc = 0.5f * (hcos_rev(r * (1.0f / 16.0f)) + 1.0f);
            // ln = log(1 + eta2/r^2); mu = log(r) - ln/2
            float ln = LN2F * hlog2(1.0f + ETA2 * hrcp(r * r));
            float lr = LN2F * hlog2(r);
            s_r[j] = r;
            s_fc[j] = fc;
            s_mu[j] = lr - 0.5f * ln;
            s_i2ln[j] = LOG2E / (2.0f * ln);
            // fc * r^-1.8 / sqrt(ln)
            s_pref[j] = fc * hexp2(-1.8f * hlog2(r)) * hrsq(ln);
        } else {
            s_r[j] = 1.0f; s_fc[j] = 0.0f; s_mu[j] = 0.0f;
            s_i2ln[j] = 1.0f; s_pref[j] = 0.0f;
        }
    }
    __syncthreads();

    // ---- phase 2: histogram pair buckets ----
    for (int idx = tid; idx < NCOMB; idx += 256) {
        int j, k; decode_pair(idx, j, k);
        if (s_win[j] && s_win[k]) {
            int pj = sspec[j], pk = sspec[k];
            int p = min(pj, pk), q = max(pj, pk);
            int P = p * NSPEC - (p * (p - 1)) / 2 + (q - p);
            atomicAdd(&cntP[P], 1);
        }
    }
    __syncthreads();
    if (tid == 0) {
        int acc = 0;
        #pragma unroll
        for (int p = 0; p < NPAIR; ++p) {
            baseP[p] = acc; curP[p] = acc; acc += cntP[p];
        }
    }
    __syncthreads();

    // ---- phase 3: compute pair geometry, scatter into P-sorted LDS ----
    for (int idx = tid; idx < NCOMB; idx += 256) {
        int j, k; decode_pair(idx, j, k);
        if (!(s_win[j] && s_win[k])) continue;

        float rij = s_r[j], rik = s_r[k];
        float dx = sx[j] - sx[k], dy = sy[j] - sy[k], dz = szc[j] - szc[k];
        float rjk = sqrtf(dx * dx + dy * dy + dz * dz);

        float rij2 = rij * rij, rik2 = rik * rik, rjk2 = rjk * rjk;
        float cos_i = (rij2 + rik2 - rjk2) * 0.5f * hrcp(rij * rik);
        float cos_j = (rij2 + rjk2 - rik2) * 0.5f * hrcp(rij * rjk);
        float cos_k = (rik2 + rjk2 - rij2) * 0.5f * hrcp(rik * rjk);

        float atm = (1.0f + 3.0f * cos_i * cos_j * cos_k)
                    * hexp2(-0.57f * hlog2(rij * rik * rjk));
        float w = W3 * atm * s_fc[j] * s_fc[k];

        float c = fminf(fmaxf(cos_i, -1.0f), 1.0f);
        float sn = sqrtf(fminf(fmaxf(1.0f - c * c, 1e-12f), 1.0f));

        int pj = sspec[j], pk = sspec[k];
        int p = min(pj, pk), q = max(pj, pk);
        int P = p * NSPEC - (p * (p - 1)) / 2 + (q - p);

        int slot = atomicAdd(&curP[P], 1);
        s_pair[slot] = make_float4(0.5f * (rij + rik), 2.0f * c * w, 2.0f * sn * w, 0.0f);
    }
    __syncthreads();

    float* orow = out + (size_t)(b * MAXN + i) * OUT_LEN;

    // ---- phase 4a: three-body gather — thread owns one (P,l) bin ----
    if (tid < NPAIR * NRS3) {
        const int P = tid / NRS3;
        const int l = tid % NRS3;
        const float rs = 0.4f * (float)(l + 1);
        float acc0 = 0.0f, acc1 = 0.0f;
        const int s0 = baseP[P], s1 = s0 + cntP[P];
        for (int s = s0; s < s1; ++s) {
            float4 pd = s_pair[s];
            float dd = pd.x - rs;
            float e = hexp2(-(ETA3 * LOG2E) * dd * dd);
            acc0 += pd.y * e;
            acc1 += pd.z * e;
        }
        orow[REP2_LEN + P * (NRS3 * 2) + l * 2 + 0] = acc0;
        orow[REP2_LEN + P * (NRS3 * 2) + l * 2 + 1] = acc1;
    }

    // ---- phase 4b: two-body — threads 160..255 own one (s,m) output ----
    if (tid >= 160) {
        const int t2 = tid - 160;          // 0..95
        const int sp = t2 / NRS2;
        const int m = t2 % NRS2;
        const float rs2 = (float)(m + 1) * (8.0f / 24.0f);
        const float lrs2 = LN2F * hlog2(rs2);
        const float nrm = 0.3989422804014327f / rs2;   // 1/(sqrt(2pi)*rs2)
        float acc = 0.0f;
        #pragma unroll
        for (int j = 0; j < MAXN; ++j) {
            if (s_win[j] && sspec[j] == sp) {
                float d = lrs2 - s_mu[j];
                acc += s_pref[j] * hexp2(-d * d * s_i2ln[j]);
            }
        }
        orow[sp * NRS2 + m] = acc * nrm;
    }
}

extern "C" void kernel_launch(void* const* d_in, const int* in_sizes, int n_in,
                              void* d_out, int out_size, void* d_ws, size_t ws_size,
                              hipStream_t stream) {
    const float* X = (const float*)d_in[0];
    const float* Z = (const float*)d_in[1];
    // d_in[2] = atomIDs, d_in[3] = molIDs (unused by reference math)
    const int* counts = (const int*)d_in[4];
    float* out = (float*)d_out;

    dim3 grid(MAXN, B_MOL);   // one block per (atom i, molecule b)
    dim3 block(256);
    hipLaunchKernelGGL(fchl_kernel, grid, block, 0, stream, X, Z, counts, out);
}